// Round 1
// baseline (233.697 us; speedup 1.0000x reference)
//
#include <hip/hip_runtime.h>
#include <hip/hip_bf16.h>

// Problem constants (from reference)
#define V 50000
#define D 128
#define B 2048
#define P 20

// Stage-1 GEMM tiling: x[B][D] = inputs[B][V] @ W_emb[D][V]^T, split-K
#define BM 128
#define BN 128          // == D, whole N in one tile
#define BK 64
#define KC 1024         // K-range per block (split-K chunk)
#define NSPLIT ((V + KC - 1) / KC)   // 49
#define LDK (BK + 8)    // padded LDS stride in bf16 elems (144 B: kills 16-way bank conflict)

typedef float  f32x4  __attribute__((ext_vector_type(4)));
typedef short  bf16x8 __attribute__((ext_vector_type(8)));

__device__ __forceinline__ unsigned short f2bf(float f) {
    unsigned int u = __float_as_uint(f);
    unsigned int r = (u + 0x7FFFu + ((u >> 16) & 1u)) >> 16;   // RNE, finite inputs
    return (unsigned short)r;
}

// ---------------- stage 1: split-K bf16 MFMA GEMM ----------------
__global__ __launch_bounds__(256, 2)
void w2v_gemm_splitk(const float* __restrict__ Ain, const float* __restrict__ Wemb,
                     float* __restrict__ part, int use_atomic) {
    __shared__ unsigned short As[BM][LDK];
    __shared__ unsigned short Ws[BN][LDK];

    const int mtile = blockIdx.x & 15;     // 16 m-tiles
    const int s     = blockIdx.x >> 4;     // split index
    const int m0    = mtile * BM;
    const int k0    = s * KC;
    const int k1    = (k0 + KC < V) ? (k0 + KC) : V;

    const int tid  = threadIdx.x;
    const int lane = tid & 63;
    const int wid  = tid >> 6;
    const int wr   = wid >> 1;             // wave row (0..1) -> 64 rows each
    const int wc   = wid & 1;              // wave col (0..1) -> 64 cols each

    f32x4 acc[4][4] = {};

    for (int ks = k0; ks < k1; ks += BK) {
        // ---- stage A(128xBK) and W(128xBK) fp32 -> bf16 LDS, padded stride ----
#pragma unroll
        for (int i = 0; i < 8; ++i) {
            int idx = tid + i * 256;       // 0..2047 float4 slots (128 rows x 16)
            int row = idx >> 4;
            int kv  = idx & 15;
            int kg  = ks + kv * 4;
            float4 av = make_float4(0.f, 0.f, 0.f, 0.f);
            float4 wv = make_float4(0.f, 0.f, 0.f, 0.f);
            if (kg < k1) {                 // k1 multiple of 16 -> whole float4 valid
                av = *reinterpret_cast<const float4*>(&Ain[(size_t)(m0 + row) * V + kg]);
                wv = *reinterpret_cast<const float4*>(&Wemb[(size_t)row * V + kg]);
            }
            ushort4 a4, w4;
            a4.x = f2bf(av.x); a4.y = f2bf(av.y); a4.z = f2bf(av.z); a4.w = f2bf(av.w);
            w4.x = f2bf(wv.x); w4.y = f2bf(wv.y); w4.z = f2bf(wv.z); w4.w = f2bf(wv.w);
            *reinterpret_cast<ushort4*>(&As[row][kv * 4]) = a4;
            *reinterpret_cast<ushort4*>(&Ws[row][kv * 4]) = w4;
        }
        __syncthreads();

        // ---- MFMA inner loop ----
#pragma unroll
        for (int kk = 0; kk < BK; kk += 32) {
            const int kfo = kk + (lane >> 4) * 8;     // 8 contiguous k per lane
            bf16x8 af[4], wf[4];
#pragma unroll
            for (int m = 0; m < 4; ++m)
                af[m] = *reinterpret_cast<const bf16x8*>(&As[wr * 64 + m * 16 + (lane & 15)][kfo]);
#pragma unroll
            for (int n = 0; n < 4; ++n)
                wf[n] = *reinterpret_cast<const bf16x8*>(&Ws[wc * 64 + n * 16 + (lane & 15)][kfo]);
#pragma unroll
            for (int m = 0; m < 4; ++m)
#pragma unroll
                for (int n = 0; n < 4; ++n)
                    acc[m][n] = __builtin_amdgcn_mfma_f32_16x16x32_bf16(af[m], wf[n], acc[m][n], 0, 0, 0);
        }
        __syncthreads();
    }

    // ---- epilogue: C/D layout col = lane&15, row = (lane>>4)*4 + j ----
    float* outp = use_atomic ? part : (part + (size_t)s * (B * D));
#pragma unroll
    for (int m = 0; m < 4; ++m) {
        int r0 = m0 + wr * 64 + m * 16 + (lane >> 4) * 4;
#pragma unroll
        for (int n = 0; n < 4; ++n) {
            int c0 = wc * 64 + n * 16 + (lane & 15);
#pragma unroll
            for (int j = 0; j < 4; ++j) {
                float v = acc[m][n][j];
                size_t off = (size_t)(r0 + j) * D + c0;
                if (use_atomic) atomicAdd(&outp[off], v);
                else            outp[off] = v;
            }
        }
    }
}

// ---------------- stage 2: reduce splits + gathered cls dots + BCE + mean ----------------
__global__ __launch_bounds__(256)
void w2v_loss(const float* __restrict__ part, int nsplit,
              const float* __restrict__ Wcls, const int* __restrict__ pathIdx,
              const float* __restrict__ codes, const float* __restrict__ mask,
              float* __restrict__ out) {
    const int lane = threadIdx.x & 63;
    const int wid  = threadIdx.x >> 6;
    const int b    = blockIdx.x * 4 + wid;     // one wave per sample

    // accumulate x[b][2*lane], x[b][2*lane+1] over splits
    float x0 = 0.f, x1 = 0.f;
    for (int s = 0; s < nsplit; ++s) {
        const float2 v = *reinterpret_cast<const float2*>(&part[(size_t)s * (B * D) + (size_t)b * D + lane * 2]);
        x0 += v.x; x1 += v.y;
    }

    float lsum = 0.f, msum = 0.f;
#pragma unroll
    for (int p = 0; p < P; ++p) {
        int node = pathIdx[b * P + p];
        const float2 w = *reinterpret_cast<const float2*>(&Wcls[(size_t)node * D + lane * 2]);
        float d = x0 * w.x + x1 * w.y;
#pragma unroll
        for (int off = 1; off < 64; off <<= 1)
            d += __shfl_xor(d, off, 64);
        float t  = codes[b * P + p];
        float mm = mask[b * P + p];
        float loss = fmaxf(d, 0.f) - d * t + log1pf(__expf(-fabsf(d)));
        lsum += loss * mm;
        msum += mm;
    }
    float per = (msum > 0.f) ? (lsum / msum) : 0.f;

    __shared__ float wsum[4];
    if (lane == 0) wsum[wid] = per;
    __syncthreads();
    if (threadIdx.x == 0) {
        float ssum = wsum[0] + wsum[1] + wsum[2] + wsum[3];
        atomicAdd(out, ssum * (1.0f / (float)B));
    }
}

extern "C" void kernel_launch(void* const* d_in, const int* in_sizes, int n_in,
                              void* d_out, int out_size, void* d_ws, size_t ws_size,
                              hipStream_t stream) {
    const float* inputs = (const float*)d_in[0];   // [B,V]
    const float* W_emb  = (const float*)d_in[1];   // [D,V]
    const float* W_cls  = (const float*)d_in[2];   // [V,D]
    const int*   path   = (const int*)  d_in[3];   // [B,P]
    const float* codes  = (const float*)d_in[4];   // [B,P]
    const float* mask   = (const float*)d_in[5];   // [B,P]
    float* out = (float*)d_out;

    const size_t part_need = (size_t)NSPLIT * B * D * sizeof(float);  // ~49 MB
    const int use_atomic = (ws_size < part_need) ? 1 : 0;
    float* part = (float*)d_ws;
    const int nsplit_eff = use_atomic ? 1 : NSPLIT;

    if (use_atomic)
        hipMemsetAsync(d_ws, 0, (size_t)B * D * sizeof(float), stream);
    hipMemsetAsync(d_out, 0, sizeof(float), stream);

    w2v_gemm_splitk<<<dim3(16 * NSPLIT), dim3(256), 0, stream>>>(inputs, W_emb, part, use_atomic);
    w2v_loss<<<dim3(B / 4), dim3(256), 0, stream>>>(part, nsplit_eff, W_cls, path, codes, mask, out);
}

// Round 2
// 162.354 us; speedup vs baseline: 1.4394x; 1.4394x over previous
//
#include <hip/hip_runtime.h>
#include <hip/hip_bf16.h>

// Problem constants (from reference)
#define V 50000
#define D 128
#define B 2048
#define P 20

// Stage-1 GEMM tiling: x[B][D] = inputs[B][V] @ W_emb[D][V]^T, split-K
#define BM 128
#define BN 128                  // == D, whole N in one tile
#define BK 64
#define NSPLIT 56               // 8 XCDs x 7 splits
#define KC 896                  // K-range per split (multiple of BK)
#define NMT (B / BM)            // 16 m-tiles

typedef float  f32x4   __attribute__((ext_vector_type(4)));
typedef short  bf16x8  __attribute__((ext_vector_type(8)));
typedef unsigned int uint4v __attribute__((ext_vector_type(4)));

// truncating fp32->bf16 pack of two floats into one u32 (low = a, high = b)
__device__ __forceinline__ unsigned int pk2(float a, float b) {
    return (__float_as_uint(b) & 0xFFFF0000u) | (__float_as_uint(a) >> 16);
}

// ---------------- stage 1: split-K bf16 MFMA GEMM ----------------
__global__ __launch_bounds__(256, 4)
void w2v_gemm_splitk(const float* __restrict__ Ain, const float* __restrict__ Wemb,
                     float* __restrict__ part, int use_atomic) {
    // 128 rows x 64 k, bf16, XOR-swizzled (16B granule): 16 KB each
    __shared__ unsigned short As[BM * BK];
    __shared__ unsigned short Ws[BN * BK];

    // XCD-aware mapping: all 16 m-tiles of a split on one XCD (i%8 heuristic)
    const int i     = blockIdx.x;          // 0..895
    const int xcd   = i & 7;
    const int j     = i >> 3;              // 0..111
    const int s     = xcd * 7 + (j >> 4);  // 0..55  (7 splits per XCD)
    const int mtile = j & 15;
    const int m0    = mtile * BM;
    const int k0    = s * KC;
    const int k1    = (k0 + KC < V) ? (k0 + KC) : V;   // k1 % 8 == 0 always

    const int tid  = threadIdx.x;
    const int lane = tid & 63;
    const int wid  = tid >> 6;
    const int wr   = wid >> 1;             // wave row (0..1) -> 64 rows
    const int wc   = wid & 1;              // wave col (0..1) -> 64 cols

    f32x4 acc[4][4] = {};

    for (int ks = k0; ks < k1; ks += BK) {
        // ---- stage A(128x64) and W(128x64) fp32 -> bf16 into swizzled LDS ----
        // slot covers 8 k's (16B bf16). 1024 slots per matrix, 4 iters each.
#pragma unroll
        for (int t = 0; t < 8; ++t) {
            const int slot = tid + (t & 3) * 256;   // 0..1023
            const int row  = slot >> 3;
            const int c8   = slot & 7;
            const int kg   = ks + c8 * 8;
            float4 v0 = make_float4(0.f, 0.f, 0.f, 0.f);
            float4 v1 = make_float4(0.f, 0.f, 0.f, 0.f);
            if (kg < k1) {   // kg%8==0, k1%8==0 -> full 8 valid
                const float* src = (t < 4) ? &Ain[(size_t)(m0 + row) * V + kg]
                                           : &Wemb[(size_t)row * V + kg];
                v0 = *reinterpret_cast<const float4*>(src);
                v1 = *reinterpret_cast<const float4*>(src + 4);
            }
            uint4v u;
            u.x = pk2(v0.x, v0.y);
            u.y = pk2(v0.z, v0.w);
            u.z = pk2(v1.x, v1.y);
            u.w = pk2(v1.z, v1.w);
            const unsigned dst = (unsigned)(row * 128) + (((unsigned)(c8 * 16)) ^ ((unsigned)(row & 7) << 4));
            char* base = (t < 4) ? (char*)As : (char*)Ws;
            *reinterpret_cast<uint4v*>(base + dst) = u;
        }
        __syncthreads();

        // ---- MFMA inner loop ----
#pragma unroll
        for (int kk = 0; kk < BK; kk += 32) {
            const unsigned kb = (unsigned)(kk * 2) + ((unsigned)(lane >> 4) << 4); // byte offset of 8-k group
            bf16x8 af[4], wf[4];
#pragma unroll
            for (int m = 0; m < 4; ++m) {
                const int r = wr * 64 + m * 16 + (lane & 15);
                af[m] = *reinterpret_cast<const bf16x8*>((char*)As + r * 128 + (kb ^ ((unsigned)(r & 7) << 4)));
            }
#pragma unroll
            for (int n = 0; n < 4; ++n) {
                const int r = wc * 64 + n * 16 + (lane & 15);
                wf[n] = *reinterpret_cast<const bf16x8*>((char*)Ws + r * 128 + (kb ^ ((unsigned)(r & 7) << 4)));
            }
#pragma unroll
            for (int m = 0; m < 4; ++m)
#pragma unroll
                for (int n = 0; n < 4; ++n)
                    acc[m][n] = __builtin_amdgcn_mfma_f32_16x16x32_bf16(af[m], wf[n], acc[m][n], 0, 0, 0);
        }
        __syncthreads();
    }

    // ---- epilogue: C/D layout col = lane&15, row = (lane>>4)*4 + j ----
    float* outp = use_atomic ? part : (part + (size_t)s * (B * D));
#pragma unroll
    for (int m = 0; m < 4; ++m) {
        int r0 = m0 + wr * 64 + m * 16 + (lane >> 4) * 4;
#pragma unroll
        for (int n = 0; n < 4; ++n) {
            int c0 = wc * 64 + n * 16 + (lane & 15);
#pragma unroll
            for (int jj = 0; jj < 4; ++jj) {
                float v = acc[m][n][jj];
                size_t off = (size_t)(r0 + jj) * D + c0;
                if (use_atomic) atomicAdd(&outp[off], v);
                else            outp[off] = v;
            }
        }
    }
}

// ---------------- stage 2: reduce splits + gathered cls dots + BCE + mean ----------------
__global__ __launch_bounds__(256)
void w2v_loss(const float* __restrict__ part, int nsplit,
              const float* __restrict__ Wcls, const int* __restrict__ pathIdx,
              const float* __restrict__ codes, const float* __restrict__ mask,
              float* __restrict__ out) {
    const int lane = threadIdx.x & 63;
    const int wid  = threadIdx.x >> 6;
    const int b    = blockIdx.x * 4 + wid;     // one wave per sample

    // accumulate x[b][2*lane], x[b][2*lane+1] over splits
    float x0 = 0.f, x1 = 0.f;
    for (int s = 0; s < nsplit; ++s) {
        const float2 v = *reinterpret_cast<const float2*>(&part[(size_t)s * (B * D) + (size_t)b * D + lane * 2]);
        x0 += v.x; x1 += v.y;
    }

    float lsum = 0.f, msum = 0.f;
#pragma unroll
    for (int p = 0; p < P; ++p) {
        int node = pathIdx[b * P + p];
        const float2 w = *reinterpret_cast<const float2*>(&Wcls[(size_t)node * D + lane * 2]);
        float d = x0 * w.x + x1 * w.y;
#pragma unroll
        for (int off = 1; off < 64; off <<= 1)
            d += __shfl_xor(d, off, 64);
        float t  = codes[b * P + p];
        float mm = mask[b * P + p];
        float loss = fmaxf(d, 0.f) - d * t + log1pf(__expf(-fabsf(d)));
        lsum += loss * mm;
        msum += mm;
    }
    float per = (msum > 0.f) ? (lsum / msum) : 0.f;

    __shared__ float wsum[4];
    if (lane == 0) wsum[wid] = per;
    __syncthreads();
    if (threadIdx.x == 0) {
        float ssum = wsum[0] + wsum[1] + wsum[2] + wsum[3];
        atomicAdd(out, ssum * (1.0f / (float)B));
    }
}

extern "C" void kernel_launch(void* const* d_in, const int* in_sizes, int n_in,
                              void* d_out, int out_size, void* d_ws, size_t ws_size,
                              hipStream_t stream) {
    const float* inputs = (const float*)d_in[0];   // [B,V]
    const float* W_emb  = (const float*)d_in[1];   // [D,V]
    const float* W_cls  = (const float*)d_in[2];   // [V,D]
    const int*   path   = (const int*)  d_in[3];   // [B,P]
    const float* codes  = (const float*)d_in[4];   // [B,P]
    const float* mask   = (const float*)d_in[5];   // [B,P]
    float* out = (float*)d_out;

    const size_t part_need = (size_t)NSPLIT * B * D * sizeof(float);  // ~59 MB
    const int use_atomic = (ws_size < part_need) ? 1 : 0;
    float* part = (float*)d_ws;
    const int nsplit_eff = use_atomic ? 1 : NSPLIT;

    if (use_atomic)
        hipMemsetAsync(d_ws, 0, (size_t)B * D * sizeof(float), stream);
    hipMemsetAsync(d_out, 0, sizeof(float), stream);

    w2v_gemm_splitk<<<dim3(NMT * NSPLIT), dim3(256), 0, stream>>>(inputs, W_emb, part, use_atomic);
    w2v_loss<<<dim3(B / 4), dim3(256), 0, stream>>>(part, nsplit_eff, W_cls, path, codes, mask, out);
}